// Round 1
// baseline (911.406 us; speedup 1.0000x reference)
//
#include <hip/hip_runtime.h>

typedef unsigned short u16;
typedef short bf16x8 __attribute__((ext_vector_type(8)));
typedef float f32x4 __attribute__((ext_vector_type(4)));

static __device__ __forceinline__ u16 f2bf(float f) {
  union { float f; unsigned u; } a; a.f = f;
  unsigned r = a.u + 0x7fffu + ((a.u >> 16) & 1u);  // RNE
  return (u16)(r >> 16);
}

static __device__ __forceinline__ bf16x8 as_bf(int4 v) {
  union { int4 i; bf16x8 b; } u; u.i = v; return u.b;
}

// ---------------- fp32 -> bf16 elementwise (x) ----------------
__global__ __launch_bounds__(256) void cvt_f32_bf16(const float* __restrict__ in,
                                                    u16* __restrict__ out, int n8) {
  int i = blockIdx.x * 256 + threadIdx.x;
  if (i >= n8) return;
  const float4* p = (const float4*)in + (size_t)i * 2;
  float4 a = p[0], b = p[1];
  union { u16 s[8]; int4 v; } u2;
  u2.s[0] = f2bf(a.x); u2.s[1] = f2bf(a.y); u2.s[2] = f2bf(a.z); u2.s[3] = f2bf(a.w);
  u2.s[4] = f2bf(b.x); u2.s[5] = f2bf(b.y); u2.s[6] = f2bf(b.z); u2.s[7] = f2bf(b.w);
  ((int4*)out)[i] = u2.v;
}

// ---------------- W (R x C fp32) -> Wt (C x R bf16) ----------------
// thread: one output 32-element chunk. Reads coalesced across lanes (consecutive c),
// writes one aligned 64B chunk per thread.
__global__ __launch_bounds__(256) void transpose_w(const float* __restrict__ in,
                                                   u16* __restrict__ out, int R, int C) {
  int T = blockIdx.x * 256 + threadIdx.x;
  int c = T % C;
  int rg = T / C;
  int r0 = rg * 32;
  __align__(16) u16 tmp[32];
#pragma unroll
  for (int j = 0; j < 32; ++j) tmp[j] = f2bf(in[(size_t)(r0 + j) * C + c]);
#pragma unroll
  for (int q = 0; q < 4; ++q)
    *(int4*)(out + (size_t)c * R + r0 + q * 8) = *(int4*)&tmp[q * 8];
}

// ---------------- V (8192 x 2048 bf16) -> Vt [bh*256+e][1024] ----------------
__global__ __launch_bounds__(256) void transpose_v(const u16* __restrict__ V,
                                                   u16* __restrict__ Vt) {
  int T = blockIdx.x * 256 + threadIdx.x;
  int e = T & 255, tg = (T >> 8) & 31, bh = T >> 13;
  int b = bh >> 3, h = bh & 7;
  const u16* src = V + (size_t)(b * 1024 + tg * 32) * 2048 + h * 256 + e;
  __align__(16) u16 tmp[32];
#pragma unroll
  for (int j = 0; j < 32; ++j) tmp[j] = src[(size_t)j * 2048];
  u16* dst = Vt + (size_t)(bh * 256 + e) * 1024 + tg * 32;
#pragma unroll
  for (int q = 0; q < 4; ++q) *(int4*)(dst + q * 8) = *(int4*)&tmp[q * 8];
}

// ---------------- GEMM: C(MxN) = A(MxK bf16) * Bt(NxK bf16)^T + bias ----------------
// 4 waves in 2x2; LDS tiles [rows][BK=64] with +16 bf16 pad (row stride 80 = 10 int4)
// and 8-element XOR swizzle -> ~2-way conflicts on staging writes and frag reads.
template <int BM, int BN, bool OUTBF>
__global__ __launch_bounds__(256) void gemm_bt(const u16* __restrict__ A,
                                               const u16* __restrict__ Bt,
                                               const float* __restrict__ bias,
                                               void* __restrict__ Cout,
                                               int M, int N, int K) {
  constexpr int BK = 64;
  constexpr int TM = BM / 2 / 16, TN = BN / 2 / 16;
  __shared__ int4 As4[BM * 10];
  __shared__ int4 Bs4[BN * 10];
  const int tid = threadIdx.x;
  const int w = tid >> 6, lane = tid & 63, lq = lane & 15, quad = lane >> 4;
  const int wm = w >> 1, wn = w & 1;
  const int m0 = blockIdx.y * BM, n0 = blockIdx.x * BN;

  f32x4 acc[TM][TN];
#pragma unroll
  for (int mi = 0; mi < TM; ++mi)
#pragma unroll
    for (int ni = 0; ni < TN; ++ni) {
      f32x4 z = {0.f, 0.f, 0.f, 0.f};
      acc[mi][ni] = z;
    }

  for (int k0 = 0; k0 < K; k0 += BK) {
    __syncthreads();
#pragma unroll
    for (int it = 0; it < BM * BK / 2048; ++it) {
      int idx = tid + it * 256;
      int r = idx >> 3, cb = idx & 7;
      As4[r * 10 + (cb ^ (r & 7))] =
          *(const int4*)(A + (size_t)(m0 + r) * K + k0 + cb * 8);
    }
#pragma unroll
    for (int it = 0; it < BN * BK / 2048; ++it) {
      int idx = tid + it * 256;
      int r = idx >> 3, cb = idx & 7;
      Bs4[r * 10 + (cb ^ (r & 7))] =
          *(const int4*)(Bt + (size_t)(n0 + r) * K + k0 + cb * 8);
    }
    __syncthreads();
#pragma unroll
    for (int kk = 0; kk < BK / 32; ++kk) {
      int4 af[TM], bf[TN];
#pragma unroll
      for (int mi = 0; mi < TM; ++mi) {
        int r = wm * (BM / 2) + mi * 16 + lq;
        af[mi] = As4[r * 10 + ((kk * 4 + quad) ^ (r & 7))];
      }
#pragma unroll
      for (int ni = 0; ni < TN; ++ni) {
        int r = wn * (BN / 2) + ni * 16 + lq;
        bf[ni] = Bs4[r * 10 + ((kk * 4 + quad) ^ (r & 7))];
      }
#pragma unroll
      for (int mi = 0; mi < TM; ++mi)
#pragma unroll
        for (int ni = 0; ni < TN; ++ni)
          acc[mi][ni] = __builtin_amdgcn_mfma_f32_16x16x32_bf16(
              as_bf(af[mi]), as_bf(bf[ni]), acc[mi][ni], 0, 0, 0);
    }
  }

#pragma unroll
  for (int mi = 0; mi < TM; ++mi)
#pragma unroll
    for (int ni = 0; ni < TN; ++ni)
#pragma unroll
      for (int r = 0; r < 4; ++r) {
        int row = m0 + wm * (BM / 2) + mi * 16 + quad * 4 + r;
        int col = n0 + wn * (BN / 2) + ni * 16 + lq;
        float v = acc[mi][ni][r] + bias[col];
        if constexpr (OUTBF)
          ((u16*)Cout)[(size_t)row * N + col] = f2bf(v);
        else
          ((float*)Cout)[(size_t)row * N + col] = v;
      }
}

// ---------------- flash attention, strictly causal (j >= i masked) ----------------
// grid (16 q-tiles, 64 b*h), 256 threads = 4 waves, each wave owns 16 query rows.
__global__ __launch_bounds__(256) void attn_kernel(const u16* __restrict__ Q,
                                                   const u16* __restrict__ Km,
                                                   const u16* __restrict__ Vt,
                                                   u16* __restrict__ O) {
  const int qt = blockIdx.x;
  const int bh = blockIdx.y;
  const int b = bh >> 3, h = bh & 7;
  const int tid = threadIdx.x;
  const int w = tid >> 6, lane = tid & 63, lq = lane & 15, quad = lane >> 4;

  __shared__ __align__(16) short Ps[4][16 * 80];

  // Q fragments (A-operand): row m = lq within wave's 16-row tile
  const u16* qptr =
      Q + (size_t)(b * 1024 + qt * 64 + w * 16 + lq) * 2048 + h * 256 + quad * 8;
  int4 qf[8];
#pragma unroll
  for (int kk = 0; kk < 8; ++kk) qf[kk] = *(const int4*)(qptr + kk * 32);

  f32x4 of[16];
#pragma unroll
  for (int i = 0; i < 16; ++i) {
    f32x4 z = {0.f, 0.f, 0.f, 0.f};
    of[i] = z;
  }
  float mst[4], lst[4];
#pragma unroll
  for (int r = 0; r < 4; ++r) { mst[r] = -__builtin_inff(); lst[r] = 0.f; }

  const int irow_base = qt * 64 + w * 16 + quad * 4;  // + r = global query index

  for (int kt = 0; kt <= qt; ++kt) {
    // ---- S = Q K^T ----
    f32x4 sc[4];
    const u16* kptr =
        Km + (size_t)(b * 1024 + kt * 64 + lq) * 2048 + h * 256 + quad * 8;
#pragma unroll
    for (int ns = 0; ns < 4; ++ns) {
      f32x4 a = {0.f, 0.f, 0.f, 0.f};
#pragma unroll
      for (int kk = 0; kk < 8; ++kk) {
        int4 kfrag = *(const int4*)(kptr + (size_t)ns * 16 * 2048 + kk * 32);
        a = __builtin_amdgcn_mfma_f32_16x16x32_bf16(as_bf(qf[kk]), as_bf(kfrag),
                                                    a, 0, 0, 0);
      }
      sc[ns] = a;
    }
    // scale + causal mask
#pragma unroll
    for (int ns = 0; ns < 4; ++ns) {
      int jcol = kt * 64 + ns * 16 + lq;
#pragma unroll
      for (int r = 0; r < 4; ++r) {
        float v = sc[ns][r] * 0.0625f;
        if (jcol >= irow_base + r) v = -__builtin_inff();
        sc[ns][r] = v;
      }
    }
    // online softmax per row (rows quad*4+r, replicated over 16-lane groups)
    float alpha[4];
#pragma unroll
    for (int r = 0; r < 4; ++r) {
      float m = fmaxf(fmaxf(sc[0][r], sc[1][r]), fmaxf(sc[2][r], sc[3][r]));
#pragma unroll
      for (int off = 8; off >= 1; off >>= 1) m = fmaxf(m, __shfl_xor(m, off, 16));
      float mn = fmaxf(mst[r], m);
      bool dead = (mn == -__builtin_inff());
      alpha[r] = dead ? 1.f : __expf(mst[r] - mn);
      mst[r] = mn;
      float s = 0.f;
#pragma unroll
      for (int ns = 0; ns < 4; ++ns) {
        float p = dead ? 0.f : __expf(sc[ns][r] - mn);
        sc[ns][r] = p;
        s += p;
      }
#pragma unroll
      for (int off = 8; off >= 1; off >>= 1) s += __shfl_xor(s, off, 16);
      lst[r] = lst[r] * alpha[r] + s;
    }
    // rescale O
#pragma unroll
    for (int i = 0; i < 16; ++i)
#pragma unroll
      for (int r = 0; r < 4; ++r) of[i][r] *= alpha[r];

    // P: C-layout -> LDS (bf16, swizzled) -> A-layout fragments
    __syncthreads();
#pragma unroll
    for (int ns = 0; ns < 4; ++ns)
#pragma unroll
      for (int r = 0; r < 4; ++r) {
        int row = quad * 4 + r;
        int col = ns * 16 + lq;
        Ps[w][row * 80 + (((col >> 3) ^ (row & 7)) << 3) + (col & 7)] =
            (short)f2bf(sc[ns][r]);
      }
    __syncthreads();
    int4 pf[2];
#pragma unroll
    for (int kk2 = 0; kk2 < 2; ++kk2) {
      int blk = kk2 * 4 + quad;
      pf[kk2] = *(const int4*)&Ps[w][lq * 80 + ((blk ^ (lq & 7)) << 3)];
    }
    // O += P V   (B-operand = Vt rows: [n=dim][k=key], direct global 16B loads)
    const u16* vptr = Vt + (size_t)(bh * 256 + lq) * 1024 + kt * 64 + quad * 8;
#pragma unroll
    for (int ns2 = 0; ns2 < 16; ++ns2)
#pragma unroll
      for (int kk2 = 0; kk2 < 2; ++kk2) {
        int4 vfrag = *(const int4*)(vptr + (size_t)ns2 * 16 * 1024 + kk2 * 32);
        of[ns2] = __builtin_amdgcn_mfma_f32_16x16x32_bf16(as_bf(pf[kk2]),
                                                          as_bf(vfrag),
                                                          of[ns2], 0, 0, 0);
      }
  }

  float inv[4];
#pragma unroll
  for (int r = 0; r < 4; ++r) inv[r] = lst[r] > 0.f ? 1.f / lst[r] : 0.f;
  u16* optr = O + (size_t)(b * 1024 + irow_base) * 2048 + h * 256 + lq;
#pragma unroll
  for (int ns2 = 0; ns2 < 16; ++ns2)
#pragma unroll
    for (int r = 0; r < 4; ++r)
      optr[(size_t)r * 2048 + ns2 * 16] = f2bf(of[ns2][r] * inv[r]);
}

// ---------------- workspace layout (bytes) ----------------
// XB 0 (4MB) | WQT 4MB | WKT 5MB | WVT 6MB | WUT 7MB | QW 8MB (32MB)
// KW 40MB | VW 72MB (32MB, reused as OW) | VTW 104MB | end ~136MB
#define WS_XB 0
#define WS_WQT 4194304
#define WS_WKT 5242880
#define WS_WVT 6291456
#define WS_WUT 7340032
#define WS_QW 8388608
#define WS_KW 41943040
#define WS_VW 75497472
#define WS_OW 75497472  /* alias: V's lifetime ends before O's begins */
#define WS_VTW 109051904

extern "C" void kernel_launch(void* const* d_in, const int* in_sizes, int n_in,
                              void* d_out, int out_size, void* d_ws, size_t ws_size,
                              hipStream_t stream) {
  const float* x = (const float*)d_in[0];
  const float* Wq = (const float*)d_in[1];
  const float* bq = (const float*)d_in[2];
  const float* Wk = (const float*)d_in[3];
  const float* bk = (const float*)d_in[4];
  const float* Wv = (const float*)d_in[5];
  const float* bv = (const float*)d_in[6];
  const float* Wu = (const float*)d_in[7];
  const float* bu = (const float*)d_in[8];
  float* out = (float*)d_out;

  char* ws = (char*)d_ws;
  u16* Xb = (u16*)(ws + WS_XB);
  u16* Wqt = (u16*)(ws + WS_WQT);
  u16* Wkt = (u16*)(ws + WS_WKT);
  u16* Wvt = (u16*)(ws + WS_WVT);
  u16* Wut = (u16*)(ws + WS_WUT);
  u16* Qw = (u16*)(ws + WS_QW);
  u16* Kw = (u16*)(ws + WS_KW);
  u16* Vw = (u16*)(ws + WS_VW);
  u16* Ow = (u16*)(ws + WS_OW);
  u16* Vtw = (u16*)(ws + WS_VTW);

  // 1) casts / transposes of inputs
  cvt_f32_bf16<<<1024, 256, 0, stream>>>(x, Xb, 262144);
  transpose_w<<<64, 256, 0, stream>>>(Wq, Wqt, 256, 2048);
  transpose_w<<<64, 256, 0, stream>>>(Wk, Wkt, 256, 2048);
  transpose_w<<<64, 256, 0, stream>>>(Wv, Wvt, 256, 2048);
  transpose_w<<<64, 256, 0, stream>>>(Wu, Wut, 2048, 256);

  // 2) QKV projections (bf16 out, fused bias)
  gemm_bt<128, 128, true><<<dim3(16, 64), 256, 0, stream>>>(Xb, Wqt, bq, Qw, 8192, 2048, 256);
  gemm_bt<128, 128, true><<<dim3(16, 64), 256, 0, stream>>>(Xb, Wkt, bk, Kw, 8192, 2048, 256);
  gemm_bt<128, 128, true><<<dim3(16, 64), 256, 0, stream>>>(Xb, Wvt, bv, Vw, 8192, 2048, 256);

  // 3) V -> V^T per (b,h)
  transpose_v<<<2048, 256, 0, stream>>>(Vw, Vtw);

  // 4) causal flash attention
  attn_kernel<<<dim3(16, 64), 256, 0, stream>>>(Qw, Kw, Vtw, Ow);

  // 5) output projection (fp32 out, fused bias)
  gemm_bt<128, 64, false><<<dim3(4, 64), 256, 0, stream>>>(Ow, Wut, bu, out, 8192, 256, 2048);
}

// Round 2
// 412.488 us; speedup vs baseline: 2.2095x; 2.2095x over previous
//
#include <hip/hip_runtime.h>

typedef unsigned short u16;
typedef short bf16x8 __attribute__((ext_vector_type(8)));
typedef float f32x4 __attribute__((ext_vector_type(4)));

static __device__ __forceinline__ u16 f2bf(float f) {
  union { float f; unsigned u; } a; a.f = f;
  unsigned r = a.u + 0x7fffu + ((a.u >> 16) & 1u);  // RNE
  return (u16)(r >> 16);
}

static __device__ __forceinline__ bf16x8 as_bf(int4 v) {
  union { int4 i; bf16x8 b; } u; u.i = v; return u.b;
}

// ---------------- fp32 -> bf16 elementwise (x) ----------------
__global__ __launch_bounds__(256) void cvt_f32_bf16(const float* __restrict__ in,
                                                    u16* __restrict__ out, int n8) {
  int i = blockIdx.x * 256 + threadIdx.x;
  if (i >= n8) return;
  const float4* p = (const float4*)in + (size_t)i * 2;
  float4 a = p[0], b = p[1];
  union { u16 s[8]; int4 v; } u2;
  u2.s[0] = f2bf(a.x); u2.s[1] = f2bf(a.y); u2.s[2] = f2bf(a.z); u2.s[3] = f2bf(a.w);
  u2.s[4] = f2bf(b.x); u2.s[5] = f2bf(b.y); u2.s[6] = f2bf(b.z); u2.s[7] = f2bf(b.w);
  ((int4*)out)[i] = u2.v;
}

// ---------------- W (R x C fp32) -> Wt (C x R bf16) ----------------
__global__ __launch_bounds__(256) void transpose_w(const float* __restrict__ in,
                                                   u16* __restrict__ out, int R, int C) {
  int T = blockIdx.x * 256 + threadIdx.x;
  int c = T % C;
  int rg = T / C;
  int r0 = rg * 32;
  __align__(16) u16 tmp[32];
#pragma unroll
  for (int j = 0; j < 32; ++j) tmp[j] = f2bf(in[(size_t)(r0 + j) * C + c]);
#pragma unroll
  for (int q = 0; q < 4; ++q)
    *(int4*)(out + (size_t)c * R + r0 + q * 8) = *(int4*)&tmp[q * 8];
}

// ---------------- V (8192 x 2048 bf16) -> Vt [bh*256+e][1024] ----------------
__global__ __launch_bounds__(256) void transpose_v(const u16* __restrict__ V,
                                                   u16* __restrict__ Vt) {
  int T = blockIdx.x * 256 + threadIdx.x;
  int e = T & 255, tg = (T >> 8) & 31, bh = T >> 13;
  int b = bh >> 3, h = bh & 7;
  const u16* src = V + (size_t)(b * 1024 + tg * 32) * 2048 + h * 256 + e;
  __align__(16) u16 tmp[32];
#pragma unroll
  for (int j = 0; j < 32; ++j) tmp[j] = src[(size_t)j * 2048];
  u16* dst = Vt + (size_t)(bh * 256 + e) * 1024 + tg * 32;
#pragma unroll
  for (int q = 0; q < 4; ++q) *(int4*)(dst + q * 8) = *(int4*)&tmp[q * 8];
}

// ---------------- GEMM: C(MxN) = A(MxK bf16) * Bt(NxK bf16)^T + bias ----------------
template <int BM, int BN, bool OUTBF>
__global__ __launch_bounds__(256) void gemm_bt(const u16* __restrict__ A,
                                               const u16* __restrict__ Bt,
                                               const float* __restrict__ bias,
                                               void* __restrict__ Cout,
                                               int M, int N, int K) {
  constexpr int BK = 64;
  constexpr int TM = BM / 2 / 16, TN = BN / 2 / 16;
  __shared__ int4 As4[BM * 10];
  __shared__ int4 Bs4[BN * 10];
  const int tid = threadIdx.x;
  const int w = tid >> 6, lane = tid & 63, lq = lane & 15, quad = lane >> 4;
  const int wm = w >> 1, wn = w & 1;
  const int m0 = blockIdx.y * BM, n0 = blockIdx.x * BN;

  f32x4 acc[TM][TN];
#pragma unroll
  for (int mi = 0; mi < TM; ++mi)
#pragma unroll
    for (int ni = 0; ni < TN; ++ni) {
      f32x4 z = {0.f, 0.f, 0.f, 0.f};
      acc[mi][ni] = z;
    }

  for (int k0 = 0; k0 < K; k0 += BK) {
    __syncthreads();
#pragma unroll
    for (int it = 0; it < BM * BK / 2048; ++it) {
      int idx = tid + it * 256;
      int r = idx >> 3, cb = idx & 7;
      As4[r * 10 + (cb ^ (r & 7))] =
          *(const int4*)(A + (size_t)(m0 + r) * K + k0 + cb * 8);
    }
#pragma unroll
    for (int it = 0; it < BN * BK / 2048; ++it) {
      int idx = tid + it * 256;
      int r = idx >> 3, cb = idx & 7;
      Bs4[r * 10 + (cb ^ (r & 7))] =
          *(const int4*)(Bt + (size_t)(n0 + r) * K + k0 + cb * 8);
    }
    __syncthreads();
#pragma unroll
    for (int kk = 0; kk < BK / 32; ++kk) {
      int4 af[TM], bf[TN];
#pragma unroll
      for (int mi = 0; mi < TM; ++mi) {
        int r = wm * (BM / 2) + mi * 16 + lq;
        af[mi] = As4[r * 10 + ((kk * 4 + quad) ^ (r & 7))];
      }
#pragma unroll
      for (int ni = 0; ni < TN; ++ni) {
        int r = wn * (BN / 2) + ni * 16 + lq;
        bf[ni] = Bs4[r * 10 + ((kk * 4 + quad) ^ (r & 7))];
      }
#pragma unroll
      for (int mi = 0; mi < TM; ++mi)
#pragma unroll
        for (int ni = 0; ni < TN; ++ni)
          acc[mi][ni] = __builtin_amdgcn_mfma_f32_16x16x32_bf16(
              as_bf(af[mi]), as_bf(bf[ni]), acc[mi][ni], 0, 0, 0);
    }
  }

#pragma unroll
  for (int mi = 0; mi < TM; ++mi)
#pragma unroll
    for (int ni = 0; ni < TN; ++ni)
#pragma unroll
      for (int r = 0; r < 4; ++r) {
        int row = m0 + wm * (BM / 2) + mi * 16 + quad * 4 + r;
        int col = n0 + wn * (BN / 2) + ni * 16 + lq;
        float v = acc[mi][ni][r] + bias[col];
        if constexpr (OUTBF)
          ((u16*)Cout)[(size_t)row * N + col] = f2bf(v);
        else
          ((float*)Cout)[(size_t)row * N + col] = v;
      }
}

// ---------------- flash attention, strictly causal (j >= i masked) ----------------
// grid (64 b*h, 16 q-tiles REVERSED for LPT), 256 threads = 4 waves, 16 q-rows/wave.
// K-tile (64x256) and Vt-tile (256x64) staged in LDS, shared by the 4 waves.
// Ps (P round-trip buffer) aliases the K-tile region (dead after QK^T).
// LDS = 34816 + 40960 = 75776 B -> 2 blocks/CU.
__global__ __launch_bounds__(256, 2) void attn_kernel(const u16* __restrict__ Q,
                                                      const u16* __restrict__ Km,
                                                      const u16* __restrict__ Vt,
                                                      u16* __restrict__ O) {
  const int bh = blockIdx.x;
  const int qt = 15 - blockIdx.y;  // heavy tiles dispatch first (LPT)
  const int b = bh >> 3, h = bh & 7;
  const int tid = threadIdx.x;
  const int w = tid >> 6, lane = tid & 63, lq = lane & 15, quad = lane >> 4;

  __shared__ __align__(16) char smem[75776];
  int4* Ks4 = (int4*)smem;              // 64 rows x 34 int4 = 34816 B
  short* Ps = (short*)smem;             // aliases K region (10240 B used)
  int4* Vs4 = (int4*)(smem + 34816);    // 256 rows x 10 int4 = 40960 B
  short* myPs = Ps + w * 1280;

  // Q fragments (A-operand), kept in registers for the whole kernel
  const u16* qptr =
      Q + (size_t)(b * 1024 + qt * 64 + w * 16 + lq) * 2048 + h * 256 + quad * 8;
  int4 qf[8];
#pragma unroll
  for (int kk = 0; kk < 8; ++kk) qf[kk] = *(const int4*)(qptr + kk * 32);

  f32x4 of[16];
#pragma unroll
  for (int i = 0; i < 16; ++i) {
    f32x4 z = {0.f, 0.f, 0.f, 0.f};
    of[i] = z;
  }
  float mst[4], lst[4];
#pragma unroll
  for (int r = 0; r < 4; ++r) { mst[r] = -__builtin_inff(); lst[r] = 0.f; }

  const int irow_base = qt * 64 + w * 16 + quad * 4;

  // staging index decomposition (same for every kt)
  const int krow = tid >> 5, kc32 = tid & 31;          // K: 2048 int4 over 8 iters
  const int vrow = tid >> 3, vcb = tid & 7;            // V: 2048 int4 over 8 iters

  for (int kt = 0; kt <= qt; ++kt) {
    // ---- issue global loads for this tile (before the barrier: overlaps prev PV)
    int4 kreg[8], vreg[8];
    const u16* ksrc = Km + (size_t)(b * 1024 + kt * 64 + krow) * 2048 + h * 256 + kc32 * 8;
    const u16* vsrc = Vt + (size_t)(bh * 256 + vrow) * 1024 + kt * 64 + vcb * 8;
#pragma unroll
    for (int it = 0; it < 8; ++it)
      kreg[it] = *(const int4*)(ksrc + (size_t)(it * 8) * 2048);
#pragma unroll
    for (int it = 0; it < 8; ++it)
      vreg[it] = *(const int4*)(vsrc + (size_t)(it * 32) * 1024);

    __syncthreads();  // previous iteration's LDS reads complete
#pragma unroll
    for (int it = 0; it < 8; ++it) {
      int r = krow + it * 8;
      int g = kc32 >> 3, p = kc32 & 7;
      Ks4[r * 34 + g * 8 + (p ^ (r & 7))] = kreg[it];
    }
#pragma unroll
    for (int it = 0; it < 8; ++it) {
      int r = vrow + it * 32;
      Vs4[r * 10 + (vcb ^ (r & 7))] = vreg[it];
    }
    __syncthreads();  // staging visible

    // ---- S = Q K^T (K fragments from LDS) ----
    f32x4 sc[4];
#pragma unroll
    for (int ns = 0; ns < 4; ++ns) {
      f32x4 a = {0.f, 0.f, 0.f, 0.f};
      int r = ns * 16 + lq;
#pragma unroll
      for (int kk = 0; kk < 8; ++kk) {
        int kb = kk * 4 + quad;
        int4 kfrag = Ks4[r * 34 + (kb >> 3) * 8 + ((kb & 7) ^ (lq & 7))];
        a = __builtin_amdgcn_mfma_f32_16x16x32_bf16(as_bf(qf[kk]), as_bf(kfrag),
                                                    a, 0, 0, 0);
      }
      sc[ns] = a;
    }
    // scale + causal mask
#pragma unroll
    for (int ns = 0; ns < 4; ++ns) {
      int jcol = kt * 64 + ns * 16 + lq;
#pragma unroll
      for (int r = 0; r < 4; ++r) {
        float v = sc[ns][r] * 0.0625f;
        if (jcol >= irow_base + r) v = -__builtin_inff();
        sc[ns][r] = v;
      }
    }
    // online softmax per row
    float alpha[4];
#pragma unroll
    for (int r = 0; r < 4; ++r) {
      float m = fmaxf(fmaxf(sc[0][r], sc[1][r]), fmaxf(sc[2][r], sc[3][r]));
#pragma unroll
      for (int off = 8; off >= 1; off >>= 1) m = fmaxf(m, __shfl_xor(m, off, 16));
      float mn = fmaxf(mst[r], m);
      bool dead = (mn == -__builtin_inff());
      alpha[r] = dead ? 1.f : __expf(mst[r] - mn);
      mst[r] = mn;
      float s = 0.f;
#pragma unroll
      for (int ns = 0; ns < 4; ++ns) {
        float p = dead ? 0.f : __expf(sc[ns][r] - mn);
        sc[ns][r] = p;
        s += p;
      }
#pragma unroll
      for (int off = 8; off >= 1; off >>= 1) s += __shfl_xor(s, off, 16);
      lst[r] = lst[r] * alpha[r] + s;
    }
    // rescale O
#pragma unroll
    for (int i = 0; i < 16; ++i)
#pragma unroll
      for (int r = 0; r < 4; ++r) of[i][r] *= alpha[r];

    // ---- P: C-layout -> LDS (aliases K region; K reads are done) ----
    __syncthreads();  // all waves finished reading Ks4
#pragma unroll
    for (int ns = 0; ns < 4; ++ns)
#pragma unroll
      for (int r = 0; r < 4; ++r) {
        int row = quad * 4 + r;
        int col = ns * 16 + lq;
        myPs[row * 80 + (((col >> 3) ^ (row & 7)) << 3) + (col & 7)] =
            (short)f2bf(sc[ns][r]);
      }
    __syncthreads();
    int4 pf[2];
#pragma unroll
    for (int kk2 = 0; kk2 < 2; ++kk2) {
      int blk = kk2 * 4 + quad;
      pf[kk2] = *(const int4*)&myPs[lq * 80 + ((blk ^ (lq & 7)) << 3)];
    }
    // ---- O += P V (V fragments from LDS) ----
#pragma unroll
    for (int ns2 = 0; ns2 < 16; ++ns2) {
      int r = ns2 * 16 + lq;
#pragma unroll
      for (int kk2 = 0; kk2 < 2; ++kk2) {
        int4 vfrag = Vs4[r * 10 + ((kk2 * 4 + quad) ^ (lq & 7))];
        of[ns2] = __builtin_amdgcn_mfma_f32_16x16x32_bf16(as_bf(pf[kk2]),
                                                          as_bf(vfrag),
                                                          of[ns2], 0, 0, 0);
      }
    }
    __syncthreads();  // V/P reads done before next iteration's staging writes
  }

  float inv[4];
#pragma unroll
  for (int r = 0; r < 4; ++r) inv[r] = lst[r] > 0.f ? 1.f / lst[r] : 0.f;
  u16* optr = O + (size_t)(b * 1024 + irow_base) * 2048 + h * 256 + lq;
#pragma unroll
  for (int ns2 = 0; ns2 < 16; ++ns2)
#pragma unroll
    for (int r = 0; r < 4; ++r)
      optr[(size_t)r * 2048 + ns2 * 16] = f2bf(of[ns2][r] * inv[r]);
}

// ---------------- workspace layout (bytes) ----------------
#define WS_XB 0
#define WS_WQT 4194304
#define WS_WKT 5242880
#define WS_WVT 6291456
#define WS_WUT 7340032
#define WS_QW 8388608
#define WS_KW 41943040
#define WS_VW 75497472
#define WS_OW 75497472  /* alias: V's lifetime ends before O's begins */
#define WS_VTW 109051904

extern "C" void kernel_launch(void* const* d_in, const int* in_sizes, int n_in,
                              void* d_out, int out_size, void* d_ws, size_t ws_size,
                              hipStream_t stream) {
  const float* x = (const float*)d_in[0];
  const float* Wq = (const float*)d_in[1];
  const float* bq = (const float*)d_in[2];
  const float* Wk = (const float*)d_in[3];
  const float* bk = (const float*)d_in[4];
  const float* Wv = (const float*)d_in[5];
  const float* bv = (const float*)d_in[6];
  const float* Wu = (const float*)d_in[7];
  const float* bu = (const float*)d_in[8];
  float* out = (float*)d_out;

  char* ws = (char*)d_ws;
  u16* Xb = (u16*)(ws + WS_XB);
  u16* Wqt = (u16*)(ws + WS_WQT);
  u16* Wkt = (u16*)(ws + WS_WKT);
  u16* Wvt = (u16*)(ws + WS_WVT);
  u16* Wut = (u16*)(ws + WS_WUT);
  u16* Qw = (u16*)(ws + WS_QW);
  u16* Kw = (u16*)(ws + WS_KW);
  u16* Vw = (u16*)(ws + WS_VW);
  u16* Ow = (u16*)(ws + WS_OW);
  u16* Vtw = (u16*)(ws + WS_VTW);

  // 1) casts / transposes of inputs
  cvt_f32_bf16<<<1024, 256, 0, stream>>>(x, Xb, 262144);
  transpose_w<<<64, 256, 0, stream>>>(Wq, Wqt, 256, 2048);
  transpose_w<<<64, 256, 0, stream>>>(Wk, Wkt, 256, 2048);
  transpose_w<<<64, 256, 0, stream>>>(Wv, Wvt, 256, 2048);
  transpose_w<<<64, 256, 0, stream>>>(Wu, Wut, 2048, 256);

  // 2) QKV projections (bf16 out, fused bias)
  gemm_bt<128, 128, true><<<dim3(16, 64), 256, 0, stream>>>(Xb, Wqt, bq, Qw, 8192, 2048, 256);
  gemm_bt<128, 128, true><<<dim3(16, 64), 256, 0, stream>>>(Xb, Wkt, bk, Kw, 8192, 2048, 256);
  gemm_bt<128, 128, true><<<dim3(16, 64), 256, 0, stream>>>(Xb, Wvt, bv, Vw, 8192, 2048, 256);

  // 3) V -> V^T per (b,h)
  transpose_v<<<2048, 256, 0, stream>>>(Vw, Vtw);

  // 4) causal flash attention (LDS-staged K/V tiles)
  attn_kernel<<<dim3(64, 16), 256, 0, stream>>>(Qw, Kw, Vtw, Ow);

  // 5) output projection (fp32 out, fused bias)
  gemm_bt<128, 64, false><<<dim3(4, 64), 256, 0, stream>>>(Ow, Wut, bu, out, 8192, 256, 2048);
}

// Round 3
// 247.542 us; speedup vs baseline: 3.6818x; 1.6663x over previous
//
#include <hip/hip_runtime.h>

typedef unsigned short u16;
typedef short bf16x8 __attribute__((ext_vector_type(8)));
typedef float f32x4 __attribute__((ext_vector_type(4)));

static __device__ __forceinline__ u16 f2bf(float f) {
  union { float f; unsigned u; } a; a.f = f;
  unsigned r = a.u + 0x7fffu + ((a.u >> 16) & 1u);  // RNE
  return (u16)(r >> 16);
}

static __device__ __forceinline__ bf16x8 as_bf(int4 v) {
  union { int4 i; bf16x8 b; } u; u.i = v; return u.b;
}

// async global->LDS, 16B per lane; LDS dest = wave-uniform base + lane*16
#define GLDS16(g, l)                                         \
  __builtin_amdgcn_global_load_lds(                          \
      (const __attribute__((address_space(1))) void*)(g),    \
      (__attribute__((address_space(3))) void*)(l), 16, 0, 0)

// ---------------- fp32 -> bf16 elementwise (x) ----------------
__global__ __launch_bounds__(256) void cvt_f32_bf16(const float* __restrict__ in,
                                                    u16* __restrict__ out, int n8) {
  int i = blockIdx.x * 256 + threadIdx.x;
  if (i >= n8) return;
  const float4* p = (const float4*)in + (size_t)i * 2;
  float4 a = p[0], b = p[1];
  union { u16 s[8]; int4 v; } u2;
  u2.s[0] = f2bf(a.x); u2.s[1] = f2bf(a.y); u2.s[2] = f2bf(a.z); u2.s[3] = f2bf(a.w);
  u2.s[4] = f2bf(b.x); u2.s[5] = f2bf(b.y); u2.s[6] = f2bf(b.z); u2.s[7] = f2bf(b.w);
  ((int4*)out)[i] = u2.v;
}

// ---------------- W (R x C fp32) -> Wt (C x R bf16) ----------------
__global__ __launch_bounds__(256) void transpose_w(const float* __restrict__ in,
                                                   u16* __restrict__ out, int R, int C) {
  int T = blockIdx.x * 256 + threadIdx.x;
  int c = T % C;
  int rg = T / C;
  int r0 = rg * 32;
  __align__(16) u16 tmp[32];
#pragma unroll
  for (int j = 0; j < 32; ++j) tmp[j] = f2bf(in[(size_t)(r0 + j) * C + c]);
#pragma unroll
  for (int q = 0; q < 4; ++q)
    *(int4*)(out + (size_t)c * R + r0 + q * 8) = *(int4*)&tmp[q * 8];
}

// ---------------- V (8192 x 2048 bf16) -> Vt [bh*256+e][1024] ----------------
__global__ __launch_bounds__(256) void transpose_v(const u16* __restrict__ V,
                                                   u16* __restrict__ Vt) {
  int T = blockIdx.x * 256 + threadIdx.x;
  int e = T & 255, tg = (T >> 8) & 31, bh = T >> 13;
  int b = bh >> 3, h = bh & 7;
  const u16* src = V + (size_t)(b * 1024 + tg * 32) * 2048 + h * 256 + e;
  __align__(16) u16 tmp[32];
#pragma unroll
  for (int j = 0; j < 32; ++j) tmp[j] = src[(size_t)j * 2048];
  u16* dst = Vt + (size_t)(bh * 256 + e) * 1024 + tg * 32;
#pragma unroll
  for (int q = 0; q < 4; ++q) *(int4*)(dst + q * 8) = *(int4*)&tmp[q * 8];
}

// ---------------- GEMM: C(MxN) = A(MxK) * Bt(NxK)^T + bias, global_load_lds staging ----
// LDS tiles [rows][8 int4], stored col c holds global int4-col (c ^ (r&7)).
// Staging swizzle implemented by permuting per-lane GLOBAL addresses.
template <int BM, int BN, bool OUTBF>
__global__ __launch_bounds__(256) void gemm_bt(const u16* __restrict__ A,
                                               const u16* __restrict__ Bt,
                                               const float* __restrict__ bias0,
                                               const float* __restrict__ bias1,
                                               const float* __restrict__ bias2,
                                               void* __restrict__ Cout,
                                               int M, int N, int K) {
  constexpr int BK = 64;
  constexpr int TM = BM / 2 / 16, TN = BN / 2 / 16;
  constexpr int nA = BM / 32, nB = BN / 32;  // global_load_lds calls per wave
  __shared__ int4 As4[BM * 8];
  __shared__ int4 Bs4[BN * 8];
  const int tid = threadIdx.x;
  const int w = tid >> 6, lane = tid & 63, lq = lane & 15, quad = lane >> 4;
  const int wm = w >> 1, wn = w & 1;
  const int m0 = blockIdx.y * BM, n0 = blockIdx.x * BN;
  const int z = blockIdx.z;

  const u16* Btz = Bt + (size_t)z * N * K;
  const float* bias = (z == 0) ? bias0 : (z == 1 ? bias1 : bias2);

  // per-lane staging geometry: slot = i*64 + lane -> row i*8 + (lane>>3), swz col lane&7
  const int srow = lane >> 3;                       // 0..7
  const int scb = (lane & 7) ^ ((lane >> 3) & 7);   // global int4-col (swizzled)

  f32x4 acc[TM][TN];
#pragma unroll
  for (int mi = 0; mi < TM; ++mi)
#pragma unroll
    for (int ni = 0; ni < TN; ++ni) {
      f32x4 z4 = {0.f, 0.f, 0.f, 0.f};
      acc[mi][ni] = z4;
    }

  for (int k0 = 0; k0 < K; k0 += BK) {
    __syncthreads();  // prior LDS reads complete
#pragma unroll
    for (int it = 0; it < nA; ++it) {
      int r = (w * nA + it) * 8 + srow;
      GLDS16(A + (size_t)(m0 + r) * K + k0 + scb * 8,
             (char*)As4 + (w * nA + it) * 1024);
    }
#pragma unroll
    for (int it = 0; it < nB; ++it) {
      int r = (w * nB + it) * 8 + srow;
      GLDS16(Btz + (size_t)(n0 + r) * K + k0 + scb * 8,
             (char*)Bs4 + (w * nB + it) * 1024);
    }
    __syncthreads();  // drains vmcnt: staged tiles visible
#pragma unroll
    for (int kk = 0; kk < BK / 32; ++kk) {
      int4 af[TM], bf[TN];
#pragma unroll
      for (int mi = 0; mi < TM; ++mi) {
        int r = wm * (BM / 2) + mi * 16 + lq;
        af[mi] = As4[r * 8 + ((kk * 4 + quad) ^ (lq & 7))];
      }
#pragma unroll
      for (int ni = 0; ni < TN; ++ni) {
        int r = wn * (BN / 2) + ni * 16 + lq;
        bf[ni] = Bs4[r * 8 + ((kk * 4 + quad) ^ (lq & 7))];
      }
#pragma unroll
      for (int mi = 0; mi < TM; ++mi)
#pragma unroll
        for (int ni = 0; ni < TN; ++ni)
          acc[mi][ni] = __builtin_amdgcn_mfma_f32_16x16x32_bf16(
              as_bf(af[mi]), as_bf(bf[ni]), acc[mi][ni], 0, 0, 0);
    }
  }

#pragma unroll
  for (int mi = 0; mi < TM; ++mi)
#pragma unroll
    for (int ni = 0; ni < TN; ++ni)
#pragma unroll
      for (int r = 0; r < 4; ++r) {
        int row = m0 + wm * (BM / 2) + mi * 16 + quad * 4 + r;
        int col = n0 + wn * (BN / 2) + ni * 16 + lq;
        float v = acc[mi][ni][r] + bias[col];
        if constexpr (OUTBF)
          ((u16*)Cout)[(size_t)z * M * N + (size_t)row * N + col] = f2bf(v);
        else
          ((float*)Cout)[(size_t)row * N + col] = v;
      }
}

// ---------------- flash attention, strictly causal, S^T formulation ----------------
// S^T = K*Q^T (A=K from LDS, B=Q in regs); O^T = V^T*P^T (A=V^T from LDS, B=P^T via
// per-wave LDS round-trip). Only ONE MFMA operand hits shared LDS.
// grid (64 bh, 16 q-tiles LPT-reversed), 256 thr = 4 waves x 16 queries.
// LDS: K 32KB + V^T 32KB + Ps 8KB = 72KB -> 2 blocks/CU.
__global__ __launch_bounds__(256, 2) void attn_kernel(const u16* __restrict__ Q,
                                                      const u16* __restrict__ Km,
                                                      const u16* __restrict__ Vt,
                                                      u16* __restrict__ O) {
  const int bh = blockIdx.x;
  const int qt = 15 - blockIdx.y;  // heavy tiles first (LPT)
  const int b = bh >> 3, h = bh & 7;
  const int tid = threadIdx.x;
  const int w = tid >> 6, lane = tid & 63, lq = lane & 15, quad = lane >> 4;

  __shared__ int4 Ks4[2048];   // 64 key-rows x 32 int4 (256 dims), swizzled
  __shared__ int4 Vs4[2048];   // 256 e-rows  x  8 int4 (64 keys), swizzled
  __shared__ u16 Ps[4096];     // per-wave 16x64 P round-trip, swizzled
  u16* myPs = Ps + w * 1024;

  // Q B-fragments: lane holds Q[query=lq][kk*32 + quad*8 + j]
  const int qg = qt * 64 + w * 16 + lq;  // this lane's query index
  const u16* qptr = Q + (size_t)(b * 1024 + qg) * 2048 + h * 256 + quad * 8;
  int4 qf[8];
#pragma unroll
  for (int kk = 0; kk < 8; ++kk) qf[kk] = *(const int4*)(qptr + kk * 32);

  // staging geometry (global-address-side swizzle)
  int koffb[8], voffb[8];
  {
    const int kg = (lane & 31) >> 3;  // int4 group within K row
#pragma unroll
    for (int it = 0; it < 8; ++it) {
      int r = w * 16 + it * 2 + (lane >> 5);       // K row 0..63
      int p = (lane & 7) ^ (r & 7);
      koffb[it] = r * 2048 + (kg * 8 + p) * 8;
      int rv = w * 64 + it * 8 + (lane >> 3);      // V^T row 0..255
      int cb = (lane & 7) ^ (rv & 7);
      voffb[it] = rv * 1024 + cb * 8;
    }
  }
  const u16* kbase = Km + (size_t)b * 1024 * 2048 + h * 256;
  const u16* vbase = Vt + (size_t)bh * 256 * 1024;

  f32x4 of[16];
#pragma unroll
  for (int i = 0; i < 16; ++i) {
    f32x4 z = {0.f, 0.f, 0.f, 0.f};
    of[i] = z;
  }
  float mst = -__builtin_inff(), lst = 0.f;

  for (int kt = 0; kt <= qt; ++kt) {
    __syncthreads();  // [A] all waves done reading Ks4/Vs4 from prev iter
    {
      const u16* kb = kbase + (size_t)kt * 64 * 2048;
      const u16* vb = vbase + kt * 64;
#pragma unroll
      for (int it = 0; it < 8; ++it)
        GLDS16(kb + koffb[it], (char*)Ks4 + (w * 8 + it) * 1024);
#pragma unroll
      for (int it = 0; it < 8; ++it)
        GLDS16(vb + voffb[it], (char*)Vs4 + (w * 8 + it) * 1024);
    }
    __syncthreads();  // [B] vmcnt drained; tiles visible

    // ---- S^T = K Q^T : D[key-local][query] ----
    f32x4 sc[4];
#pragma unroll
    for (int ns = 0; ns < 4; ++ns) {
      f32x4 a = {0.f, 0.f, 0.f, 0.f};
      int r = ns * 16 + lq;
#pragma unroll
      for (int kk = 0; kk < 8; ++kk) {
        int G = kk * 4 + quad;
        int4 kf = Ks4[r * 32 + (G >> 3) * 8 + ((G & 7) ^ (lq & 7))];
        a = __builtin_amdgcn_mfma_f32_16x16x32_bf16(as_bf(kf), as_bf(qf[kk]),
                                                    a, 0, 0, 0);
      }
      sc[ns] = a;
    }
    // scale + strictly-causal mask (key >= query -> -inf)
#pragma unroll
    for (int ns = 0; ns < 4; ++ns) {
      int keyb = kt * 64 + ns * 16 + quad * 4;
#pragma unroll
      for (int r = 0; r < 4; ++r) {
        float v = sc[ns][r] * 0.0625f;
        sc[ns][r] = (keyb + r >= qg) ? -__builtin_inff() : v;
      }
    }
    // online softmax (per lane = per query, replicated x4 over quad groups)
    float m16 = sc[0][0];
#pragma unroll
    for (int ns = 0; ns < 4; ++ns)
#pragma unroll
      for (int r = 0; r < 4; ++r) m16 = fmaxf(m16, sc[ns][r]);
    m16 = fmaxf(m16, __shfl_xor(m16, 16));
    m16 = fmaxf(m16, __shfl_xor(m16, 32));
    float mn = fmaxf(mst, m16);
    bool dead = (mn == -__builtin_inff());
    float alpha = dead ? 1.f : __expf(mst - mn);
    mst = mn;
    float s = 0.f;
#pragma unroll
    for (int ns = 0; ns < 4; ++ns)
#pragma unroll
      for (int r = 0; r < 4; ++r) {
        float p = dead ? 0.f : __expf(sc[ns][r] - mn);
        sc[ns][r] = p;
        s += p;
      }
    s += __shfl_xor(s, 16);
    s += __shfl_xor(s, 32);
    lst = lst * alpha + s;
#pragma unroll
    for (int i = 0; i < 16; ++i)
#pragma unroll
      for (int r = 0; r < 4; ++r) of[i][r] *= alpha;

    // ---- P^T C-layout -> B-layout via per-wave LDS (no barriers needed) ----
#pragma unroll
    for (int ns = 0; ns < 4; ++ns) {
      int kb = ns * 2 + (quad >> 1);
      int base = lq * 64 + (kb ^ (lq & 7)) * 8 + (quad & 1) * 4;
#pragma unroll
      for (int h2 = 0; h2 < 2; ++h2) {
        unsigned d = (unsigned)f2bf(sc[ns][2 * h2]) |
                     ((unsigned)f2bf(sc[ns][2 * h2 + 1]) << 16);
        *(unsigned*)&myPs[base + 2 * h2] = d;
      }
    }
    int4 pf[2];
#pragma unroll
    for (int kk2 = 0; kk2 < 2; ++kk2) {
      int kbp = (kk2 * 4 + quad) ^ (lq & 7);
      pf[kk2] = *(const int4*)&myPs[lq * 64 + kbp * 8];
    }
    // ---- O^T += V^T P^T ----
#pragma unroll
    for (int ns2 = 0; ns2 < 16; ++ns2) {
      int r = ns2 * 16 + lq;
#pragma unroll
      for (int kk2 = 0; kk2 < 2; ++kk2) {
        int4 vf = Vs4[r * 8 + ((kk2 * 4 + quad) ^ (lq & 7))];
        of[ns2] = __builtin_amdgcn_mfma_f32_16x16x32_bf16(as_bf(vf), as_bf(pf[kk2]),
                                                          of[ns2], 0, 0, 0);
      }
    }
  }

  float inv = lst > 0.f ? 1.f / lst : 0.f;  // fully-masked query 0 -> zero row
  u16* optr = O + (size_t)(b * 1024 + qg) * 2048 + h * 256 + quad * 4;
#pragma unroll
  for (int ns2 = 0; ns2 < 16; ++ns2) {
    union { u16 s[4]; uint2 d; } o4;
#pragma unroll
    for (int r = 0; r < 4; ++r) o4.s[r] = f2bf(of[ns2][r] * inv);
    *(uint2*)(optr + ns2 * 16) = o4.d;
  }
}

// ---------------- workspace layout (bytes) ----------------
#define WS_XB 0
#define WS_WQT 4194304
#define WS_WKT 5242880
#define WS_WVT 6291456
#define WS_WUT 7340032
#define WS_QW 8388608
#define WS_KW 41943040
#define WS_VW 75497472
#define WS_OW 75497472  /* alias: V's lifetime ends before O's begins */
#define WS_VTW 109051904

extern "C" void kernel_launch(void* const* d_in, const int* in_sizes, int n_in,
                              void* d_out, int out_size, void* d_ws, size_t ws_size,
                              hipStream_t stream) {
  const float* x = (const float*)d_in[0];
  const float* Wq = (const float*)d_in[1];
  const float* bq = (const float*)d_in[2];
  const float* Wk = (const float*)d_in[3];
  const float* bk = (const float*)d_in[4];
  const float* Wv = (const float*)d_in[5];
  const float* bv = (const float*)d_in[6];
  const float* Wu = (const float*)d_in[7];
  const float* bu = (const float*)d_in[8];
  float* out = (float*)d_out;

  char* ws = (char*)d_ws;
  u16* Xb = (u16*)(ws + WS_XB);
  u16* Wqt = (u16*)(ws + WS_WQT);
  u16* Wkt = (u16*)(ws + WS_WKT);
  u16* Wvt = (u16*)(ws + WS_WVT);
  u16* Wut = (u16*)(ws + WS_WUT);
  u16* Qw = (u16*)(ws + WS_QW);
  u16* Vw = (u16*)(ws + WS_VW);
  u16* Ow = (u16*)(ws + WS_OW);
  u16* Vtw = (u16*)(ws + WS_VTW);
  u16* Kw = (u16*)(ws + WS_KW);

  // 1) casts / transposes of inputs
  cvt_f32_bf16<<<1024, 256, 0, stream>>>(x, Xb, 262144);
  transpose_w<<<64, 256, 0, stream>>>(Wq, Wqt, 256, 2048);
  transpose_w<<<64, 256, 0, stream>>>(Wk, Wkt, 256, 2048);
  transpose_w<<<64, 256, 0, stream>>>(Wv, Wvt, 256, 2048);
  transpose_w<<<64, 256, 0, stream>>>(Wu, Wut, 2048, 256);

  // 2) fused QKV projections (z selects Wq/Wk/Wv; Wqt/Wkt/Wvt and Qw/Kw/Vw are
  //    contiguous at fixed strides in the workspace)
  gemm_bt<128, 128, true><<<dim3(16, 64, 3), 256, 0, stream>>>(
      Xb, Wqt, bq, bk, bv, Qw, 8192, 2048, 256);

  // 3) V -> V^T per (b,h)
  transpose_v<<<2048, 256, 0, stream>>>(Vw, Vtw);

  // 4) causal flash attention (S^T formulation, async LDS staging)
  attn_kernel<<<dim3(64, 16), 256, 0, stream>>>(Qw, Kw, Vtw, Ow);

  // 5) output projection (fp32 out, fused bias)
  gemm_bt<64, 64, false><<<dim3(4, 128, 1), 256, 0, stream>>>(
      Ow, Wut, bu, bu, bu, out, 8192, 256, 2048);
}

// Round 5
// 221.633 us; speedup vs baseline: 4.1122x; 1.1169x over previous
//
#include <hip/hip_runtime.h>
#include <hip/hip_bf16.h>

typedef unsigned short u16;
typedef short bf16x8 __attribute__((ext_vector_type(8)));
typedef float f32x4 __attribute__((ext_vector_type(4)));

// 2^x via raw v_exp_f32 (NOT __exp2f: glibc math.h declares a host __exp2f,
// which collides in hipcc's merged TU)
#define EXP2(x) __builtin_amdgcn_exp2f(x)

static __device__ __forceinline__ u16 f2bf(float f) {
  union { float f; unsigned u; } a; a.f = f;
  unsigned r = a.u + 0x7fffu + ((a.u >> 16) & 1u);  // RNE
  return (u16)(r >> 16);
}

static __device__ __forceinline__ unsigned pkbf(float a, float b) {
  union { __hip_bfloat162 h; unsigned u; } c;
  c.h = __float22bfloat162_rn(make_float2(a, b));
  return c.u;  // low 16 = a, high 16 = b
}

static __device__ __forceinline__ bf16x8 as_bf(int4 v) {
  union { int4 i; bf16x8 b; } u; u.i = v; return u.b;
}

// async global->LDS, 16B per lane; LDS dest = wave-uniform base + lane*16
#define GLDS16(g, l)                                         \
  __builtin_amdgcn_global_load_lds(                          \
      (const __attribute__((address_space(1))) void*)(g),    \
      (__attribute__((address_space(3))) void*)(l), 16, 0, 0)

// ---------------- fused prep: x cast + 4 weight transposes ----------------
// blocks [0,1024): cvt x (fp32->bf16, 8 elems/thread)
// blocks [1024,1280): transpose_w for Wq/Wk/Wv/Wu (64 blocks each)
__global__ __launch_bounds__(256) void prep(
    const float* __restrict__ x, u16* __restrict__ Xb,
    const float* __restrict__ Wq, u16* __restrict__ Wqt,
    const float* __restrict__ Wk, u16* __restrict__ Wkt,
    const float* __restrict__ Wv, u16* __restrict__ Wvt,
    const float* __restrict__ Wu, u16* __restrict__ Wut) {
  const int bid = blockIdx.x, tid = threadIdx.x;
  if (bid < 1024) {
    int i = bid * 256 + tid;
    const float4* p = (const float4*)x + (size_t)i * 2;
    float4 a = p[0], b = p[1];
    union { unsigned s[4]; int4 v; } u2;
    u2.s[0] = pkbf(a.x, a.y); u2.s[1] = pkbf(a.z, a.w);
    u2.s[2] = pkbf(b.x, b.y); u2.s[3] = pkbf(b.z, b.w);
    ((int4*)Xb)[i] = u2.v;
    return;
  }
  const int which = (bid - 1024) >> 6;
  const float* in; u16* out; int R, C;
  if (which == 0)      { in = Wq; out = Wqt; R = 256;  C = 2048; }
  else if (which == 1) { in = Wk; out = Wkt; R = 256;  C = 2048; }
  else if (which == 2) { in = Wv; out = Wvt; R = 256;  C = 2048; }
  else                 { in = Wu; out = Wut; R = 2048; C = 256;  }
  int T = ((bid - 1024) & 63) * 256 + tid;
  int c = T % C;
  int r0 = (T / C) * 32;
  __align__(16) u16 tmp[32];
#pragma unroll
  for (int j = 0; j < 32; ++j) tmp[j] = f2bf(in[(size_t)(r0 + j) * C + c]);
#pragma unroll
  for (int q = 0; q < 4; ++q)
    *(int4*)(out + (size_t)c * R + r0 + q * 8) = *(int4*)&tmp[q * 8];
}

// ---------------- fused QKV GEMM (M=8192,N=2048,K=256, 128x128 tiles) ----------
// z=0 -> Q (row-major bf16), z=1 -> K (row-major), z=2 -> V^T directly
// (LDS tile transpose in the epilogue; no row-major V is ever written).
__global__ __launch_bounds__(256) void gemm_qkv(const u16* __restrict__ A,
                                                const u16* __restrict__ Wt,
                                                const float* __restrict__ bq,
                                                const float* __restrict__ bk,
                                                const float* __restrict__ bv,
                                                u16* __restrict__ Qw,
                                                u16* __restrict__ Kw,
                                                u16* __restrict__ Vt) {
  constexpr int BM = 128, BN = 128, BK = 64;
  __shared__ int4 smem4[2048];  // 32 KB: As(16K) | Bs(16K); reused for transpose
  int4* As4 = smem4;
  int4* Bs4 = smem4 + 1024;
  const int tid = threadIdx.x;
  const int w = tid >> 6, lane = tid & 63, lq = lane & 15, quad = lane >> 4;
  const int wm = w >> 1, wn = w & 1;
  const int m0 = blockIdx.y * BM, n0 = blockIdx.x * BN;
  const int z = blockIdx.z;

  const u16* Btz = Wt + (size_t)z * 2048 * 256;
  const float* bias = (z == 0) ? bq : (z == 1 ? bk : bv);

  const int srow = lane >> 3;
  const int scb = (lane & 7) ^ ((lane >> 3) & 7);

  f32x4 acc[4][4];
#pragma unroll
  for (int mi = 0; mi < 4; ++mi)
#pragma unroll
    for (int ni = 0; ni < 4; ++ni) {
      f32x4 z4 = {0.f, 0.f, 0.f, 0.f};
      acc[mi][ni] = z4;
    }

  for (int k0 = 0; k0 < 256; k0 += BK) {
    __syncthreads();
#pragma unroll
    for (int it = 0; it < 4; ++it) {
      int r = (w * 4 + it) * 8 + srow;
      GLDS16(A + (size_t)(m0 + r) * 256 + k0 + scb * 8,
             (char*)As4 + (w * 4 + it) * 1024);
    }
#pragma unroll
    for (int it = 0; it < 4; ++it) {
      int r = (w * 4 + it) * 8 + srow;
      GLDS16(Btz + (size_t)(n0 + r) * 256 + k0 + scb * 8,
             (char*)Bs4 + (w * 4 + it) * 1024);
    }
    __syncthreads();
#pragma unroll
    for (int kk = 0; kk < 2; ++kk) {
      int4 af[4], bf[4];
#pragma unroll
      for (int mi = 0; mi < 4; ++mi) {
        int r = wm * 64 + mi * 16 + lq;
        af[mi] = As4[r * 8 + ((kk * 4 + quad) ^ (lq & 7))];
      }
#pragma unroll
      for (int ni = 0; ni < 4; ++ni) {
        int r = wn * 64 + ni * 16 + lq;
        bf[ni] = Bs4[r * 8 + ((kk * 4 + quad) ^ (lq & 7))];
      }
#pragma unroll
      for (int mi = 0; mi < 4; ++mi)
#pragma unroll
        for (int ni = 0; ni < 4; ++ni)
          acc[mi][ni] = __builtin_amdgcn_mfma_f32_16x16x32_bf16(
              as_bf(af[mi]), as_bf(bf[ni]), acc[mi][ni], 0, 0, 0);
    }
  }

  if (z < 2) {
    u16* Cout = z ? Kw : Qw;
#pragma unroll
    for (int mi = 0; mi < 4; ++mi)
#pragma unroll
      for (int ni = 0; ni < 4; ++ni)
#pragma unroll
        for (int r = 0; r < 4; ++r) {
          int row = m0 + wm * 64 + mi * 16 + quad * 4 + r;
          int col = n0 + wn * 64 + ni * 16 + lq;
          Cout[(size_t)row * 2048 + col] = f2bf(acc[mi][ni][r] + bias[col]);
        }
  } else {
    // V^T epilogue: transpose the 128x128 tile through LDS, store coalesced.
    __syncthreads();  // all waves done with As4/Bs4
    u16* Ts = (u16*)smem4;
#pragma unroll
    for (int mi = 0; mi < 4; ++mi)
#pragma unroll
      for (int ni = 0; ni < 4; ++ni) {
        int c = wn * 64 + ni * 16 + lq;
        int r0 = wm * 64 + mi * 16 + quad * 4;
        float vb = bias[n0 + c];
        uint2 dd;
        dd.x = pkbf(acc[mi][ni][0] + vb, acc[mi][ni][1] + vb);
        dd.y = pkbf(acc[mi][ni][2] + vb, acc[mi][ni][3] + vb);
        *(uint2*)&Ts[c * 128 + (((r0 >> 3) ^ (c & 15)) << 3) + (r0 & 7)] = dd;
      }
    __syncthreads();
    const int b = m0 >> 10, t0 = m0 & 1023;
    const int e0 = n0 & 255, h = n0 >> 8;
    const int bh = b * 8 + h;
    const int i4 = tid & 15;
#pragma unroll
    for (int cc = 0; cc < 8; ++cc) {
      int c = (tid >> 4) + cc * 16;
      int4 val = *(const int4*)&Ts[c * 128 + ((i4 ^ (c & 15)) << 3)];
      *(int4*)(Vt + (size_t)(bh * 256 + e0 + c) * 1024 + t0 + i4 * 8) = val;
    }
  }
}

// ---------------- generic GEMM (out-projection): fp32 out + bias ----------------
template <int BM, int BN>
__global__ __launch_bounds__(256) void gemm_bt(const u16* __restrict__ A,
                                               const u16* __restrict__ Bt,
                                               const float* __restrict__ bias,
                                               float* __restrict__ Cout,
                                               int M, int N, int K) {
  constexpr int BK = 64;
  constexpr int TM = BM / 2 / 16, TN = BN / 2 / 16;
  constexpr int nA = BM / 32, nB = BN / 32;
  __shared__ int4 As4[BM * 8];
  __shared__ int4 Bs4[BN * 8];
  const int tid = threadIdx.x;
  const int w = tid >> 6, lane = tid & 63, lq = lane & 15, quad = lane >> 4;
  const int wm = w >> 1, wn = w & 1;
  const int m0 = blockIdx.y * BM, n0 = blockIdx.x * BN;

  const int srow = lane >> 3;
  const int scb = (lane & 7) ^ ((lane >> 3) & 7);

  f32x4 acc[TM][TN];
#pragma unroll
  for (int mi = 0; mi < TM; ++mi)
#pragma unroll
    for (int ni = 0; ni < TN; ++ni) {
      f32x4 z4 = {0.f, 0.f, 0.f, 0.f};
      acc[mi][ni] = z4;
    }

  for (int k0 = 0; k0 < K; k0 += BK) {
    __syncthreads();
#pragma unroll
    for (int it = 0; it < nA; ++it) {
      int r = (w * nA + it) * 8 + srow;
      GLDS16(A + (size_t)(m0 + r) * K + k0 + scb * 8,
             (char*)As4 + (w * nA + it) * 1024);
    }
#pragma unroll
    for (int it = 0; it < nB; ++it) {
      int r = (w * nB + it) * 8 + srow;
      GLDS16(Bt + (size_t)(n0 + r) * K + k0 + scb * 8,
             (char*)Bs4 + (w * nB + it) * 1024);
    }
    __syncthreads();
#pragma unroll
    for (int kk = 0; kk < BK / 32; ++kk) {
      int4 af[TM], bf[TN];
#pragma unroll
      for (int mi = 0; mi < TM; ++mi) {
        int r = wm * (BM / 2) + mi * 16 + lq;
        af[mi] = As4[r * 8 + ((kk * 4 + quad) ^ (lq & 7))];
      }
#pragma unroll
      for (int ni = 0; ni < TN; ++ni) {
        int r = wn * (BN / 2) + ni * 16 + lq;
        bf[ni] = Bs4[r * 8 + ((kk * 4 + quad) ^ (lq & 7))];
      }
#pragma unroll
      for (int mi = 0; mi < TM; ++mi)
#pragma unroll
        for (int ni = 0; ni < TN; ++ni)
          acc[mi][ni] = __builtin_amdgcn_mfma_f32_16x16x32_bf16(
              as_bf(af[mi]), as_bf(bf[ni]), acc[mi][ni], 0, 0, 0);
    }
  }

#pragma unroll
  for (int mi = 0; mi < TM; ++mi)
#pragma unroll
    for (int ni = 0; ni < TN; ++ni)
#pragma unroll
      for (int r = 0; r < 4; ++r) {
        int row = m0 + wm * (BM / 2) + mi * 16 + quad * 4 + r;
        int col = n0 + wn * (BN / 2) + ni * 16 + lq;
        Cout[(size_t)row * N + col] = acc[mi][ni][r] + bias[col];
      }
}

// ---------------- flash attention, strictly causal, S^T form, paired q-tiles ----
// grid (64 bh, 8 pairs); block processes q-tiles {p, 15-p} -> exactly 17 inner
// iterations per block (perfect balance, 512 blocks = 2/CU).
// exp2-domain softmax, finite mask (-3e38), conditional O-rescale, packed cvt.
__global__ __launch_bounds__(256, 2) void attn_kernel(const u16* __restrict__ Q,
                                                      const u16* __restrict__ Km,
                                                      const u16* __restrict__ Vt,
                                                      u16* __restrict__ O) {
  const int bh = blockIdx.x;
  const int pair = blockIdx.y;
  const int b = bh >> 3, h = bh & 7;
  const int tid = threadIdx.x;
  const int w = tid >> 6, lane = tid & 63, lq = lane & 15, quad = lane >> 4;

  __shared__ int4 Ks4[2048];   // 64 key-rows x 32 int4 (256 dims), swizzled
  __shared__ int4 Vs4[2048];   // 256 e-rows  x  8 int4 (64 keys), swizzled
  __shared__ u16 Ps[4096];     // per-wave 16x64 P round-trip
  u16* myPs = Ps + w * 1024;

  // staging geometry (global-address-side swizzle), q-tile independent
  int koffb[8], voffb[8];
  {
    const int kg = (lane & 31) >> 3;
#pragma unroll
    for (int it = 0; it < 8; ++it) {
      int r = w * 16 + it * 2 + (lane >> 5);
      int p = (lane & 7) ^ (r & 7);
      koffb[it] = r * 2048 + (kg * 8 + p) * 8;
      int rv = w * 64 + it * 8 + (lane >> 3);
      int cb = (lane & 7) ^ (rv & 7);
      voffb[it] = rv * 1024 + cb * 8;
    }
  }
  const u16* kbase = Km + (size_t)b * 2097152 + h * 256;
  const u16* vbase = Vt + (size_t)bh * 262144;

  const float SCL = 0.09016844f;  // (1/16) * log2(e): softmax in exp2 domain
  const float NEG = -3.0e38f;

#pragma unroll 1
  for (int hv = 0; hv < 2; ++hv) {
    const int qt = hv ? (15 - pair) : pair;
    const int qg = qt * 64 + w * 16 + lq;  // this lane's query index
    const u16* qptr = Q + (size_t)(b * 1024 + qg) * 2048 + h * 256 + quad * 8;
    int4 qf[8];
#pragma unroll
    for (int kk = 0; kk < 8; ++kk) qf[kk] = *(const int4*)(qptr + kk * 32);

    f32x4 of[16];
#pragma unroll
    for (int i = 0; i < 16; ++i) {
      f32x4 z = {0.f, 0.f, 0.f, 0.f};
      of[i] = z;
    }
    float mst = NEG, lst = 0.f;

    for (int kt = 0; kt <= qt; ++kt) {
      __syncthreads();  // prior iter's LDS reads complete
      {
        const u16* kb = kbase + (size_t)kt * 131072;
        const u16* vb = vbase + kt * 64;
#pragma unroll
        for (int it = 0; it < 8; ++it)
          GLDS16(kb + koffb[it], (char*)Ks4 + (w * 8 + it) * 1024);
#pragma unroll
        for (int it = 0; it < 8; ++it)
          GLDS16(vb + voffb[it], (char*)Vs4 + (w * 8 + it) * 1024);
      }
      __syncthreads();  // staged tiles visible

      // ---- S^T = K Q^T : D[key-local][query] ----
      f32x4 sc[4];
#pragma unroll
      for (int ns = 0; ns < 4; ++ns) {
        f32x4 a = {0.f, 0.f, 0.f, 0.f};
        int r = ns * 16 + lq;
#pragma unroll
        for (int kk = 0; kk < 8; ++kk) {
          int G = kk * 4 + quad;
          int4 kf = Ks4[r * 32 + (G >> 3) * 8 + ((G & 7) ^ (lq & 7))];
          a = __builtin_amdgcn_mfma_f32_16x16x32_bf16(as_bf(kf), as_bf(qf[kk]),
                                                      a, 0, 0, 0);
        }
        sc[ns] = a;
      }
      // scale (exp2 domain) + strictly-causal mask (finite NEG)
#pragma unroll
      for (int ns = 0; ns < 4; ++ns) {
        int keyb = kt * 64 + ns * 16 + quad * 4;
#pragma unroll
        for (int r = 0; r < 4; ++r) {
          float v = sc[ns][r] * SCL;
          sc[ns][r] = (keyb + r >= qg) ? NEG : v;
        }
      }
      // online softmax (per lane = per query, reduce across quad groups)
      float m16 = sc[0][0];
#pragma unroll
      for (int ns = 0; ns < 4; ++ns)
#pragma unroll
        for (int r = 0; r < 4; ++r) m16 = fmaxf(m16, sc[ns][r]);
      m16 = fmaxf(m16, __shfl_xor(m16, 16));
      m16 = fmaxf(m16, __shfl_xor(m16, 32));
      if (__any(m16 > mst)) {  // wave-uniform: skip rescale when max unchanged
        float mn = fmaxf(mst, m16);
        float alpha = EXP2(mst - mn);
        mst = mn;
        lst *= alpha;
#pragma unroll
        for (int i = 0; i < 16; ++i)
#pragma unroll
          for (int r = 0; r < 4; ++r) of[i][r] *= alpha;
      }
      float s = 0.f;
#pragma unroll
      for (int ns = 0; ns < 4; ++ns)
#pragma unroll
        for (int r = 0; r < 4; ++r) {
          float p = EXP2(sc[ns][r] - mst);
          sc[ns][r] = p;
          s += p;
        }
      s += __shfl_xor(s, 16);
      s += __shfl_xor(s, 32);
      lst += s;

      // ---- P^T C-layout -> B-layout via per-wave LDS (no barrier) ----
#pragma unroll
      for (int ns = 0; ns < 4; ++ns) {
        int kb2 = ns * 2 + (quad >> 1);
        int base = lq * 64 + ((kb2 ^ (lq & 7)) << 3) + (quad & 1) * 4;
        *(unsigned*)&myPs[base] = pkbf(sc[ns][0], sc[ns][1]);
        *(unsigned*)&myPs[base + 2] = pkbf(sc[ns][2], sc[ns][3]);
      }
      int4 pf[2];
#pragma unroll
      for (int kk2 = 0; kk2 < 2; ++kk2) {
        int kbp = (kk2 * 4 + quad) ^ (lq & 7);
        pf[kk2] = *(const int4*)&myPs[lq * 64 + kbp * 8];
      }
      // ---- O^T += V^T P^T ----
#pragma unroll
      for (int ns2 = 0; ns2 < 16; ++ns2) {
        int r = ns2 * 16 + lq;
#pragma unroll
        for (int kk2 = 0; kk2 < 2; ++kk2) {
          int4 vf = Vs4[r * 8 + ((kk2 * 4 + quad) ^ (lq & 7))];
          of[ns2] = __builtin_amdgcn_mfma_f32_16x16x32_bf16(
              as_bf(vf), as_bf(pf[kk2]), of[ns2], 0, 0, 0);
        }
      }
    }

    float inv = lst > 0.f ? 1.f / lst : 0.f;
    if (qg == 0) inv = 0.f;  // fully-masked first query -> zero row
    u16* optr = O + (size_t)(b * 1024 + qg) * 2048 + h * 256 + quad * 4;
#pragma unroll
    for (int ns2 = 0; ns2 < 16; ++ns2) {
      uint2 o4;
      o4.x = pkbf(of[ns2][0] * inv, of[ns2][1] * inv);
      o4.y = pkbf(of[ns2][2] * inv, of[ns2][3] * inv);
      *(uint2*)(optr + ns2 * 16) = o4;
    }
  }
}

// ---------------- workspace layout (bytes) ----------------
#define WS_XB 0
#define WS_WQT 4194304   /* Wqt|Wkt|Wvt contiguous, 1 MB each */
#define WS_WUT 7340032
#define WS_QW 8388608    /* 32 MB */
#define WS_KW 41943040   /* 32 MB */
#define WS_OW 75497472   /* 32 MB */
#define WS_VTW 109051904 /* 32 MB */

extern "C" void kernel_launch(void* const* d_in, const int* in_sizes, int n_in,
                              void* d_out, int out_size, void* d_ws, size_t ws_size,
                              hipStream_t stream) {
  const float* x = (const float*)d_in[0];
  const float* Wq = (const float*)d_in[1];
  const float* bq = (const float*)d_in[2];
  const float* Wk = (const float*)d_in[3];
  const float* bk = (const float*)d_in[4];
  const float* Wv = (const float*)d_in[5];
  const float* bv = (const float*)d_in[6];
  const float* Wu = (const float*)d_in[7];
  const float* bu = (const float*)d_in[8];
  float* out = (float*)d_out;

  char* ws = (char*)d_ws;
  u16* Xb = (u16*)(ws + WS_XB);
  u16* Wqt = (u16*)(ws + WS_WQT);
  u16* Wkt = Wqt + 524288;
  u16* Wvt = Wqt + 1048576;
  u16* Wut = (u16*)(ws + WS_WUT);
  u16* Qw = (u16*)(ws + WS_QW);
  u16* Kw = (u16*)(ws + WS_KW);
  u16* Ow = (u16*)(ws + WS_OW);
  u16* Vtw = (u16*)(ws + WS_VTW);

  // 1) fused prep: x cast + all weight transposes (one dispatch)
  prep<<<1280, 256, 0, stream>>>(x, Xb, Wq, Wqt, Wk, Wkt, Wv, Wvt, Wu, Wut);

  // 2) fused QKV projections; z==2 writes V^T directly (no transpose_v pass)
  gemm_qkv<<<dim3(16, 64, 3), 256, 0, stream>>>(Xb, Wqt, bq, bk, bv, Qw, Kw, Vtw);

  // 3) causal flash attention (paired q-tiles, 17 iters/block uniform)
  attn_kernel<<<dim3(64, 8), 256, 0, stream>>>(Qw, Kw, Vtw, Ow);

  // 4) output projection (fp32 out, fused bias) — 256 blocks = 1/CU
  gemm_bt<128, 64><<<dim3(4, 64), 256, 0, stream>>>(Ow, Wut, bu, out, 8192, 256, 2048);
}